// Round 8
// baseline (409.567 us; speedup 1.0000x reference)
//
#include <hip/hip_runtime.h>
#include <hip/hip_bf16.h>

typedef unsigned short u16;
typedef unsigned int   u32;
typedef short   bf16x8 __attribute__((ext_vector_type(8)));  // bf16 carried as i16
typedef float   f32x4  __attribute__((ext_vector_type(4)));

__device__ __forceinline__ float bf2f(u16 u) {
    u32 t = ((u32)u) << 16;
    return __builtin_bit_cast(float, t);
}
__device__ __forceinline__ u32 f2bf(float f) {
    u32 u = __builtin_bit_cast(u32, f);
    return (u + 0x7FFFu + ((u >> 16) & 1u)) >> 16;   // RNE
}

// ---------------------------------------------------------------------------
// Kernel 0a: offset/mask conv weights -> hi/lo bf16 A[32][2304], r = t*256+c
// oc 0..17 = w_off, 18..26 = w_mod, 27..31 = 0.
// ---------------------------------------------------------------------------
__global__ void kprep(const float* __restrict__ woff, const float* __restrict__ wmod,
                      u16* __restrict__ ah, u16* __restrict__ al) {
    int i = blockIdx.x * 256 + threadIdx.x;      // 288 blocks -> 73728 exact
    if (i >= 32 * 2304) return;
    int oc = i / 2304, r = i - oc * 2304;
    int t = r >> 8, c = r & 255;
    float v = 0.f;
    if (oc < 18)      v = woff[oc * 2304 + c * 9 + t];
    else if (oc < 27) v = wmod[(oc - 18) * 2304 + c * 9 + t];
    u32 hb = f2bf(v);
    u32 lb = f2bf(v - bf2f((u16)hb));
    ah[i] = (u16)hb;
    al[i] = (u16)lb;
}

// ---------------------------------------------------------------------------
// Kernel 0b: w_reg f32 -> bf16, REORDERED to r = t*256 + c (tap-major K).
// wregb[o][t*256+c] = bf16(wreg[o][c*9+t])
// ---------------------------------------------------------------------------
__global__ void kwreg(const float* __restrict__ wreg, u16* __restrict__ wregb) {
    int i = blockIdx.x * 256 + threadIdx.x;      // 2304 blocks exact
    int o = i / 2304, r = i - o * 2304;
    int t = r >> 8, c = r & 255;
    wregb[i] = (u16)f2bf(wreg[o * 2304 + c * 9 + t]);
}

// ---------------------------------------------------------------------------
// Kernel 1: offset/mask conv as MFMA GEMM, M=32 (27 live), N=16384, K=2304.
// hi/lo bf16 split on both operands -> 3 MFMAs, fp32-equivalent precision.
// Fused bias + 2*sigmoid epilogue writes offf directly.
// ---------------------------------------------------------------------------
__global__ __launch_bounds__(256) void koffg(const float* __restrict__ x,
                                             const u16* __restrict__ ah_g,
                                             const u16* __restrict__ al_g,
                                             const float* __restrict__ boff,
                                             const float* __restrict__ bmod,
                                             float* __restrict__ offf) {
    __shared__ u16 Ah[32 * 72], Al[32 * 72];     // 32 oc-rows, 64 k + 8 pad
    __shared__ u16 Bh[32 * 72], Bl[32 * 72];     // 32 n-rows,  64 k + 8 pad
    int tid = threadIdx.x;
    int n0 = blockIdx.x * 32;
    int b = n0 >> 12, h0 = (n0 & 4095) >> 6, w0 = n0 & 63;
    int lane = tid & 63, wv = tid >> 6;
    int mt = wv & 1, nt = wv >> 1;               // 2 m-tiles x 2 n-tiles of 16
    int col = lane & 15, quad = lane >> 4;

    int aoc = tid >> 3, ak0 = (tid & 7) * 8;     // A staging role
    int nl = tid & 31, cl0 = (tid >> 5) * 8;     // B staging role

    f32x4 acc = (f32x4){0.f, 0.f, 0.f, 0.f};

    for (int kt = 0; kt < 36; kt++) {
        int t = kt >> 2, c0 = (kt & 3) << 6;
        int r0 = kt * 64;
        int dy = t / 3 - 1, dx = t % 3 - 1;
        uint4 pah = *(const uint4*)(ah_g + aoc * 2304 + r0 + ak0);
        uint4 pal = *(const uint4*)(al_g + aoc * 2304 + r0 + ak0);
        int hp = h0 + dy, wp = w0 + nl + dx;
        bool vm = ((unsigned)hp < 64u) && ((unsigned)wp < 64u);
        int hc = min(max(hp, 0), 63), wc = min(max(wp, 0), 63);
        const float* xp = x + ((long)(b * 256 + c0 + cl0) << 12) + hc * 64 + wc;
        u32 whi[4], wlo[4];
#pragma unroll
        for (int i = 0; i < 8; i++) {
            float v = vm ? xp[(long)i << 12] : 0.f;
            u32 hb = f2bf(v);
            u32 lb = f2bf(v - bf2f((u16)hb));
            if (i & 1) { whi[i >> 1] |= hb << 16; wlo[i >> 1] |= lb << 16; }
            else       { whi[i >> 1]  = hb;       wlo[i >> 1]  = lb; }
        }
        __syncthreads();
        *(uint4*)&Ah[aoc * 72 + ak0] = pah;
        *(uint4*)&Al[aoc * 72 + ak0] = pal;
        *(uint4*)&Bh[nl * 72 + cl0] = make_uint4(whi[0], whi[1], whi[2], whi[3]);
        *(uint4*)&Bl[nl * 72 + cl0] = make_uint4(wlo[0], wlo[1], wlo[2], wlo[3]);
        __syncthreads();
#pragma unroll
        for (int ks = 0; ks < 2; ks++) {
            int ko = ks * 32 + quad * 8;
            bf16x8 fah = *(const bf16x8*)&Ah[(mt * 16 + col) * 72 + ko];
            bf16x8 fal = *(const bf16x8*)&Al[(mt * 16 + col) * 72 + ko];
            bf16x8 fbh = *(const bf16x8*)&Bh[(nt * 16 + col) * 72 + ko];
            bf16x8 fbl = *(const bf16x8*)&Bl[(nt * 16 + col) * 72 + ko];
            acc = __builtin_amdgcn_mfma_f32_16x16x32_bf16(fah, fbh, acc, 0, 0, 0);
            acc = __builtin_amdgcn_mfma_f32_16x16x32_bf16(fah, fbl, acc, 0, 0, 0);
            acc = __builtin_amdgcn_mfma_f32_16x16x32_bf16(fal, fbh, acc, 0, 0, 0);
        }
    }

    int n = n0 + nt * 16 + col;
#pragma unroll
    for (int r = 0; r < 4; r++) {
        int oc = mt * 16 + quad * 4 + r;
        float s = acc[r];
        if (oc < 18) {
            int ch = 3 * (oc >> 1) + (oc & 1);   // even oc -> dy, odd -> dx
            offf[(ch << 14) + n] = s + boff[oc];
        } else if (oc < 27) {
            float tt = s + bmod[oc - 18];
            int ch = 3 * (oc - 18) + 2;
            offf[(ch << 14) + n] = 2.f / (1.f + __expf(-tt));
        }
    }
}

// ---------------------------------------------------------------------------
// Kernel 2: FUSED deformable-sampling + GEMM + BN + ReLU.
// out[o][n] = relu(BN( sum_{t,c} wregb[o][t*256+c] * sample(x[c], tap t, n) ))
// Block: n-tile 64 (one image row), o-tile 128. Grid (256, 2) = 2 blocks/CU.
// K-order r = t*256+c (BK=64 => fixed tap per tile). B built on the fly:
// thread = (pixel nl, 16-channel group); per-tap corner weights held in regs
// (offf values for all 9 taps prefetch-rotated). Gathers for kt+1 staged in
// registers during kt's MFMA section (software pipeline).
// ---------------------------------------------------------------------------
__global__ __launch_bounds__(256) void kfuse(const float* __restrict__ x,
                                             const u16* __restrict__ wregb,
                                             const float* __restrict__ offf,
                                             const float* __restrict__ gamma,
                                             const float* __restrict__ beta,
                                             const float* __restrict__ rmean,
                                             const float* __restrict__ rvar,
                                             float* __restrict__ out) {
    __shared__ u16 Als[128 * 72];  // 128 o-rows, 64 k + 8 pad
    __shared__ u16 Bls[64 * 72];   // 64 n-rows, 64 k + 8 pad
    int tid = threadIdx.x;
    int n0 = blockIdx.x * 64;                    // one row of one image
    int o0 = blockIdx.y * 128;
    int b = n0 >> 12, h = (n0 & 4095) >> 6;
    int lane = tid & 63, wv = tid >> 6;
    int wo = (wv >> 1) * 64, wn = (wv & 1) * 32;
    int col = lane & 15, quad = lane >> 4;
    int nl = tid & 63, cg = tid >> 6;            // sampling role
    int n = n0 + nl;

    const float* xb = x + ((long)b << 20);       // image base (256 planes)

    f32x4 acc[4][2];
#pragma unroll
    for (int i = 0; i < 4; i++)
#pragma unroll
        for (int j = 0; j < 2; j++) acc[i][j] = (f32x4){0.f, 0.f, 0.f, 0.f};

    // --- tap-state helpers (per-thread pixel nl) ---
    int o00, o01, o10, o11; float s00, s01, s10, s11;
    float cdy = offf[(0 << 14) + n];
    float cdx = offf[(1 << 14) + n];
    float cm  = offf[(2 << 14) + n];
    float ndy = offf[(3 << 14) + n];             // prefetch tap 1
    float ndx = offf[(4 << 14) + n];
    float nm  = offf[(5 << 14) + n];

#define TAPSTATE(T, DY, DX, M)                                                \
    {                                                                         \
        float py = (float)(h - 1 + ((T) / 3)) + (DY);                         \
        float px = (float)(nl - 1 + ((T) % 3)) + (DX);                        \
        float y0f = floorf(py), x0f = floorf(px);                             \
        float wy = py - y0f, wx = px - x0f;                                   \
        int iy0 = (int)y0f, ix0 = (int)x0f;                                   \
        int iy1 = iy0 + 1, ix1 = ix0 + 1;                                     \
        bool vy0 = (unsigned)iy0 < 64u, vy1 = (unsigned)iy1 < 64u;            \
        bool vx0 = (unsigned)ix0 < 64u, vx1 = (unsigned)ix1 < 64u;            \
        int cy0 = min(max(iy0, 0), 63), cy1 = min(max(iy1, 0), 63);           \
        int cx0 = min(max(ix0, 0), 63), cx1 = min(max(ix1, 0), 63);           \
        o00 = cy0 * 64 + cx0; o01 = cy0 * 64 + cx1;                           \
        o10 = cy1 * 64 + cx0; o11 = cy1 * 64 + cx1;                           \
        float a = 1.f - wy, bw = 1.f - wx;                                    \
        s00 = (vy0 && vx0) ? a  * bw * (M) : 0.f;                             \
        s01 = (vy0 && vx1) ? a  * wx * (M) : 0.f;                             \
        s10 = (vy1 && vx0) ? wy * bw * (M) : 0.f;                             \
        s11 = (vy1 && vx1) ? wy * wx * (M) : 0.f;                             \
    }

#define STAGE(KT, PA, WDS)                                                    \
    {                                                                         \
        int c0s = ((KT) & 3) << 6;                                            \
        _Pragma("unroll")                                                     \
        for (int i = 0; i < 4; i++) {                                         \
            int cidx = tid + i * 256;                                         \
            int oo = cidx >> 3, qq = cidx & 7;                                \
            PA[i] = *(const uint4*)(wregb + (long)(o0 + oo) * 2304 +          \
                                    (KT) * 64 + qq * 8);                      \
        }                                                                     \
        const float* xp = xb + ((long)(c0s + cg * 16) << 12);                 \
        _Pragma("unroll")                                                     \
        for (int i = 0; i < 16; i++) {                                        \
            const float* xc = xp + ((long)i << 12);                           \
            float v = s00 * xc[o00] + s01 * xc[o01] +                         \
                      s10 * xc[o10] + s11 * xc[o11];                          \
            u32 bv = f2bf(v);                                                 \
            if (i & 1) WDS[i >> 1] |= bv << 16;                               \
            else       WDS[i >> 1]  = bv;                                     \
        }                                                                     \
    }

    TAPSTATE(0, cdy, cdx, cm)
    uint4 pa[4];
    u32 wds[8];
    STAGE(0, pa, wds)

    for (int kt = 0; kt < 36; kt++) {
        __syncthreads();
#pragma unroll
        for (int i = 0; i < 4; i++) {
            int cidx = tid + i * 256;
            int oo = cidx >> 3, qq = cidx & 7;
            *(uint4*)&Als[oo * 72 + qq * 8] = pa[i];
        }
        *(uint4*)&Bls[nl * 72 + cg * 16]     = make_uint4(wds[0], wds[1], wds[2], wds[3]);
        *(uint4*)&Bls[nl * 72 + cg * 16 + 8] = make_uint4(wds[4], wds[5], wds[6], wds[7]);
        __syncthreads();

        int kn = kt + 1;
        if (kn < 36) {
            if ((kn & 3) == 0) {                 // tap change: rotate prefetch
                int tn = kn >> 2;
                TAPSTATE(tn, ndy, ndx, nm)
                if (tn < 8) {
                    ndy = offf[((3 * tn + 3) << 14) + n];
                    ndx = offf[((3 * tn + 4) << 14) + n];
                    nm  = offf[((3 * tn + 5) << 14) + n];
                }
            }
            STAGE(kn, pa, wds)
        }

#pragma unroll
        for (int ks = 0; ks < 2; ks++) {
            bf16x8 af[4], bfr[2];
#pragma unroll
            for (int i = 0; i < 4; i++)
                af[i] = *(const bf16x8*)&Als[(wo + i * 16 + col) * 72 + ks * 32 + quad * 8];
#pragma unroll
            for (int j = 0; j < 2; j++)
                bfr[j] = *(const bf16x8*)&Bls[(wn + j * 16 + col) * 72 + ks * 32 + quad * 8];
#pragma unroll
            for (int i = 0; i < 4; i++)
#pragma unroll
                for (int j = 0; j < 2; j++)
                    acc[i][j] = __builtin_amdgcn_mfma_f32_16x16x32_bf16(
                        af[i], bfr[j], acc[i][j], 0, 0, 0);
        }
    }
#undef STAGE
#undef TAPSTATE

    // epilogue: BN + ReLU, D layout: row(o) = quad*4+reg, col(n) = lane&15
#pragma unroll
    for (int i = 0; i < 4; i++) {
        int ob = o0 + wo + i * 16 + quad * 4;
        float inv[4], add[4];
#pragma unroll
        for (int r = 0; r < 4; r++) {
            int o = ob + r;
            float iv = gamma[o] * rsqrtf(rvar[o] + 1e-5f);
            inv[r] = iv; add[r] = beta[o] - rmean[o] * iv;
        }
#pragma unroll
        for (int j = 0; j < 2; j++) {
            int n_g = n0 + wn + j * 16 + col;
            int hw = n_g & 4095;
            float* op = out + ((long)b << 20) + hw;
#pragma unroll
            for (int r = 0; r < 4; r++) {
                float v = acc[i][j][r] * inv[r] + add[r];
                v = fmaxf(v, 0.f);
                op[(long)(ob + r) << 12] = v;
            }
        }
    }
}

// ---------------------------------------------------------------------------
extern "C" void kernel_launch(void* const* d_in, const int* in_sizes, int n_in,
                              void* d_out, int out_size, void* d_ws, size_t ws_size,
                              hipStream_t stream) {
    const float* x     = (const float*)d_in[0];
    const float* woff  = (const float*)d_in[1];
    const float* boff  = (const float*)d_in[2];
    const float* wmod  = (const float*)d_in[3];
    const float* bmod  = (const float*)d_in[4];
    const float* wreg  = (const float*)d_in[5];
    const float* gamma = (const float*)d_in[6];
    const float* beta  = (const float*)d_in[7];
    const float* rmean = (const float*)d_in[8];
    const float* rvar  = (const float*)d_in[9];
    float* out = (float*)d_out;

    char* ws = (char*)d_ws;
    // ws map (total ~3.6 MB):
    //   [0x000000, 0x024000) wph   bf16  144 KB (A hi)
    //   [0x040000, 0x064000) wpl   bf16  144 KB (A lo)
    //   [0x080000, 0x23C000) offf  fp32  1.77 MB
    //   [0x240000, 0x360000) wregb bf16  1.18 MB (r = t*256+c order)
    u16*   wph   = (u16*)(ws);
    u16*   wpl   = (u16*)(ws + 0x40000u);
    float* offf  = (float*)(ws + 0x80000u);
    u16*   wregb = (u16*)(ws + 0x240000u);

    kprep<<<288,  256, 0, stream>>>(woff, wmod, wph, wpl);
    kwreg<<<2304, 256, 0, stream>>>(wreg, wregb);
    koffg<<<512,  256, 0, stream>>>(x, wph, wpl, boff, bmod, offf);
    kfuse<<<dim3(256, 2), 256, 0, stream>>>(x, wregb, offf, gamma, beta,
                                            rmean, rvar, out);
}

// Round 9
// 351.892 us; speedup vs baseline: 1.1639x; 1.1639x over previous
//
#include <hip/hip_runtime.h>
#include <hip/hip_bf16.h>

typedef unsigned short u16;
typedef unsigned int   u32;
typedef short   bf16x8 __attribute__((ext_vector_type(8)));  // bf16 carried as i16
typedef float   f32x4  __attribute__((ext_vector_type(4)));

__device__ __forceinline__ float bf2f(u16 u) {
    u32 t = ((u32)u) << 16;
    return __builtin_bit_cast(float, t);
}
__device__ __forceinline__ u32 f2bf(float f) {
    u32 u = __builtin_bit_cast(u32, f);
    return (u + 0x7FFFu + ((u >> 16) & 1u)) >> 16;   // RNE
}

// ---------------------------------------------------------------------------
// Kernel 0a: offset/mask conv weights -> hi/lo bf16 A[32][2304], r = t*256+c
// (koffg's K-order). oc 0..17 = w_off, 18..26 = w_mod, 27..31 = 0.
// ---------------------------------------------------------------------------
__global__ void kprep(const float* __restrict__ woff, const float* __restrict__ wmod,
                      u16* __restrict__ ah, u16* __restrict__ al) {
    int i = blockIdx.x * 256 + threadIdx.x;      // 288 blocks -> 73728 exact
    if (i >= 32 * 2304) return;
    int oc = i / 2304, r = i - oc * 2304;
    int t = r >> 8, c = r & 255;
    float v = 0.f;
    if (oc < 18)      v = woff[oc * 2304 + c * 9 + t];
    else if (oc < 27) v = wmod[(oc - 18) * 2304 + c * 9 + t];
    u32 hb = f2bf(v);
    u32 lb = f2bf(v - bf2f((u16)hb));
    ah[i] = (u16)hb;
    al[i] = (u16)lb;
}

// ---------------------------------------------------------------------------
// Kernel 0b: w_reg f32 -> bf16, identity layout [o][c*9+t] (matches samp).
// ---------------------------------------------------------------------------
__global__ void kwreg(const float* __restrict__ wreg, u16* __restrict__ wregb) {
    int i = blockIdx.x * 256 + threadIdx.x;      // 2304 blocks exact
    wregb[i] = (u16)f2bf(wreg[i]);
}

// ---------------------------------------------------------------------------
// Kernel 1: offset/mask conv as MFMA GEMM, M=32 (27 live), N=16384, K=2304.
// hi/lo bf16 split on both operands -> 3 MFMAs, fp32-equivalent precision.
// Fused bias + 2*sigmoid epilogue writes offf directly.
// ---------------------------------------------------------------------------
__global__ __launch_bounds__(256) void koffg(const float* __restrict__ x,
                                             const u16* __restrict__ ah_g,
                                             const u16* __restrict__ al_g,
                                             const float* __restrict__ boff,
                                             const float* __restrict__ bmod,
                                             float* __restrict__ offf) {
    __shared__ u16 Ah[32 * 72], Al[32 * 72];     // 32 oc-rows, 64 k + 8 pad
    __shared__ u16 Bh[32 * 72], Bl[32 * 72];     // 32 n-rows,  64 k + 8 pad
    int tid = threadIdx.x;
    int n0 = blockIdx.x * 32;
    int b = n0 >> 12, h0 = (n0 & 4095) >> 6, w0 = n0 & 63;
    int lane = tid & 63, wv = tid >> 6;
    int mt = wv & 1, nt = wv >> 1;               // 2 m-tiles x 2 n-tiles of 16
    int col = lane & 15, quad = lane >> 4;

    int aoc = tid >> 3, ak0 = (tid & 7) * 8;     // A staging role
    int nl = tid & 31, cl0 = (tid >> 5) * 8;     // B staging role

    f32x4 acc = (f32x4){0.f, 0.f, 0.f, 0.f};

    for (int kt = 0; kt < 36; kt++) {
        int t = kt >> 2, c0 = (kt & 3) << 6;
        int r0 = kt * 64;
        int dy = t / 3 - 1, dx = t % 3 - 1;
        uint4 pah = *(const uint4*)(ah_g + aoc * 2304 + r0 + ak0);
        uint4 pal = *(const uint4*)(al_g + aoc * 2304 + r0 + ak0);
        int hp = h0 + dy, wp = w0 + nl + dx;
        bool vm = ((unsigned)hp < 64u) && ((unsigned)wp < 64u);
        int hc = min(max(hp, 0), 63), wc = min(max(wp, 0), 63);
        const float* xp = x + ((long)(b * 256 + c0 + cl0) << 12) + hc * 64 + wc;
        u32 whi[4], wlo[4];
#pragma unroll
        for (int i = 0; i < 8; i++) {
            float v = vm ? xp[(long)i << 12] : 0.f;
            u32 hb = f2bf(v);
            u32 lb = f2bf(v - bf2f((u16)hb));
            if (i & 1) { whi[i >> 1] |= hb << 16; wlo[i >> 1] |= lb << 16; }
            else       { whi[i >> 1]  = hb;       wlo[i >> 1]  = lb; }
        }
        __syncthreads();
        *(uint4*)&Ah[aoc * 72 + ak0] = pah;
        *(uint4*)&Al[aoc * 72 + ak0] = pal;
        *(uint4*)&Bh[nl * 72 + cl0] = make_uint4(whi[0], whi[1], whi[2], whi[3]);
        *(uint4*)&Bl[nl * 72 + cl0] = make_uint4(wlo[0], wlo[1], wlo[2], wlo[3]);
        __syncthreads();
#pragma unroll
        for (int ks = 0; ks < 2; ks++) {
            int ko = ks * 32 + quad * 8;
            bf16x8 fah = *(const bf16x8*)&Ah[(mt * 16 + col) * 72 + ko];
            bf16x8 fal = *(const bf16x8*)&Al[(mt * 16 + col) * 72 + ko];
            bf16x8 fbh = *(const bf16x8*)&Bh[(nt * 16 + col) * 72 + ko];
            bf16x8 fbl = *(const bf16x8*)&Bl[(nt * 16 + col) * 72 + ko];
            acc = __builtin_amdgcn_mfma_f32_16x16x32_bf16(fah, fbh, acc, 0, 0, 0);
            acc = __builtin_amdgcn_mfma_f32_16x16x32_bf16(fah, fbl, acc, 0, 0, 0);
            acc = __builtin_amdgcn_mfma_f32_16x16x32_bf16(fal, fbh, acc, 0, 0, 0);
        }
    }

    int n = n0 + nt * 16 + col;
#pragma unroll
    for (int r = 0; r < 4; r++) {
        int oc = mt * 16 + quad * 4 + r;
        float s = acc[r];
        if (oc < 18) {
            int ch = 3 * (oc >> 1) + (oc & 1);   // even oc -> dy, odd -> dx
            offf[(ch << 14) + n] = s + boff[oc];
        } else if (oc < 27) {
            float tt = s + bmod[oc - 18];
            int ch = 3 * (oc - 18) + 2;
            offf[(ch << 14) + n] = 2.f / (1.f + __expf(-tt));
        }
    }
}

// ---------------------------------------------------------------------------
// Kernel 2: deformable bilinear sampling -> pre-fragmented samp[rb][nloc][8],
// rb = r>>3, r = c*9+k. Thread = (pixel, one 8-channel group), tap-outer
// loop with scalar tap state (low VGPR -> high occupancy for latency hiding).
// grid = dim3(NL/64, 8), block 256 (64 px x 4 c-groups of 8 ch).
// ---------------------------------------------------------------------------
__global__ __launch_bounds__(256) void ksamp(const float* __restrict__ x,
                                             const float* __restrict__ offf,
                                             u16* __restrict__ samp,
                                             int n0base, int NL) {
    int nl = threadIdx.x & 63, cg = threadIdx.x >> 6;
    int cq = (blockIdx.y << 2) | cg;            // 0..31, 8 channels each
    int nloc = blockIdx.x * 64 + nl;            // 0..NL-1
    int n = n0base + nloc;
    int b = n >> 12, hw = n & 4095, h = hw >> 6, w = hw & 63;

    u32 words[36];
#pragma unroll
    for (int i = 0; i < 36; i++) words[i] = 0u;

    const float* xb = x + ((long)(b * 256 + cq * 8) << 12);
#pragma unroll
    for (int k = 0; k < 9; k++) {
        float dy = offf[((3 * k + 0) << 14) + n];
        float dx = offf[((3 * k + 1) << 14) + n];
        float m  = offf[((3 * k + 2) << 14) + n];
        float py = (float)(h - 1 + (k / 3)) + dy;
        float px = (float)(w - 1 + (k % 3)) + dx;
        float y0f = floorf(py), x0f = floorf(px);
        float wy = py - y0f, wx = px - x0f;
        int iy0 = (int)y0f, ix0 = (int)x0f;
        int iy1 = iy0 + 1, ix1 = ix0 + 1;
        bool vy0 = (unsigned)iy0 < 64u, vy1 = (unsigned)iy1 < 64u;
        bool vx0 = (unsigned)ix0 < 64u, vx1 = (unsigned)ix1 < 64u;
        int cy0 = min(max(iy0, 0), 63), cy1 = min(max(iy1, 0), 63);
        int cx0 = min(max(ix0, 0), 63), cx1 = min(max(ix1, 0), 63);
        int o00 = cy0 * 64 + cx0, o01 = cy0 * 64 + cx1;
        int o10 = cy1 * 64 + cx0, o11 = cy1 * 64 + cx1;
        float a = 1.f - wy, bw = 1.f - wx;
        float s00 = (vy0 && vx0) ? a  * bw * m : 0.f;
        float s01 = (vy0 && vx1) ? a  * wx * m : 0.f;
        float s10 = (vy1 && vx0) ? wy * bw * m : 0.f;
        float s11 = (vy1 && vx1) ? wy * wx * m : 0.f;
#pragma unroll
        for (int cc = 0; cc < 8; cc++) {
            const float* xc = xb + ((long)cc << 12);
            float v = s00 * xc[o00] + s01 * xc[o01] +
                      s10 * xc[o10] + s11 * xc[o11];
            int e = cc * 9 + k;
            words[e >> 1] |= f2bf(v) << ((e & 1) * 16);
        }
    }
    u16* sp = samp + ((long)(cq * 9) * NL + nloc) * 8;
#pragma unroll
    for (int o = 0; o < 9; o++)
        *(uint4*)(sp + (long)o * NL * 8) =
            make_uint4(words[o * 4 + 0], words[o * 4 + 1],
                       words[o * 4 + 2], words[o * 4 + 3]);
}

// ---------------------------------------------------------------------------
// Kernel 3: GEMM for one NL-pixel chunk. Tile 128(o) x 64(n), BK=64.
// grid = dim3(NL/64, 2). Register-prefetch pipeline: kt+1's A/B global loads
// issued right after staging kt (VMEM in flight during kt's MFMA section).
// out[o][n] = relu(BN( sum_r wregb[o][r] * samp[r][nloc] ))
// ---------------------------------------------------------------------------
__global__ __launch_bounds__(256) void kgemm(const u16* __restrict__ wregb,
                                             const u16* __restrict__ samp,
                                             const float* __restrict__ gamma,
                                             const float* __restrict__ beta,
                                             const float* __restrict__ rmean,
                                             const float* __restrict__ rvar,
                                             float* __restrict__ out,
                                             int n0base, int NL) {
    __shared__ u16 Al[128 * 72];   // 128 o-rows, 64 k + 8 pad
    __shared__ u16 Bl[64 * 72];    // 64 n-rows, 64 k + 8 pad
    int tid = threadIdx.x;
    int mt = blockIdx.y, ntl = blockIdx.x;
    int o0 = mt * 128;
    int nloc0 = ntl * 64;
    int n0 = n0base + nloc0;
    int lane = tid & 63, wv = tid >> 6;
    int wo = (wv >> 1) * 64, wn = (wv & 1) * 32;
    int col = lane & 15, quad = lane >> 4;

    // staging roles
    int sao = tid >> 1, saq = (tid & 1) * 4;     // unused alt mapping (kept simple below)
    (void)sao; (void)saq;

    f32x4 acc[4][2];
#pragma unroll
    for (int i = 0; i < 4; i++)
#pragma unroll
        for (int j = 0; j < 2; j++) acc[i][j] = (f32x4){0.f, 0.f, 0.f, 0.f};

    uint4 pa[4], pb[2];
    // preload kt = 0
#pragma unroll
    for (int i = 0; i < 4; i++) {
        int cidx = tid + i * 256;
        int o = cidx >> 3, qq = cidx & 7;
        pa[i] = *(const uint4*)(wregb + (long)(o0 + o) * 2304 + qq * 8);
    }
#pragma unroll
    for (int i = 0; i < 2; i++) {
        int cidx = tid + i * 256;
        int rbl = cidx >> 6, nl2 = cidx & 63;
        pb[i] = *(const uint4*)(samp + ((long)rbl * NL + nloc0 + nl2) * 8);
    }

    for (int kt = 0; kt < 36; kt++) {
        __syncthreads();                         // prev MFMA frag reads done
#pragma unroll
        for (int i = 0; i < 4; i++) {
            int cidx = tid + i * 256;
            int o = cidx >> 3, qq = cidx & 7;
            *(uint4*)&Al[o * 72 + qq * 8] = pa[i];
        }
#pragma unroll
        for (int i = 0; i < 2; i++) {
            int cidx = tid + i * 256;
            int rbl = cidx >> 6, nl2 = cidx & 63;
            *(uint4*)&Bl[nl2 * 72 + rbl * 8] = pb[i];
        }
        __syncthreads();

        int kn = kt + 1;
        if (kn < 36) {                           // prefetch during MFMA
            int r0 = kn * 64, rb0 = kn * 8;
#pragma unroll
            for (int i = 0; i < 4; i++) {
                int cidx = tid + i * 256;
                int o = cidx >> 3, qq = cidx & 7;
                pa[i] = *(const uint4*)(wregb + (long)(o0 + o) * 2304 + r0 + qq * 8);
            }
#pragma unroll
            for (int i = 0; i < 2; i++) {
                int cidx = tid + i * 256;
                int rbl = cidx >> 6, nl2 = cidx & 63;
                pb[i] = *(const uint4*)(samp + ((long)(rb0 + rbl) * NL + nloc0 + nl2) * 8);
            }
        }

#pragma unroll
        for (int ks = 0; ks < 2; ks++) {
            bf16x8 af[4], bfr[2];
#pragma unroll
            for (int i = 0; i < 4; i++)
                af[i] = *(const bf16x8*)&Al[(wo + i * 16 + col) * 72 + ks * 32 + quad * 8];
#pragma unroll
            for (int j = 0; j < 2; j++)
                bfr[j] = *(const bf16x8*)&Bl[(wn + j * 16 + col) * 72 + ks * 32 + quad * 8];
#pragma unroll
            for (int i = 0; i < 4; i++)
#pragma unroll
                for (int j = 0; j < 2; j++)
                    acc[i][j] = __builtin_amdgcn_mfma_f32_16x16x32_bf16(
                        af[i], bfr[j], acc[i][j], 0, 0, 0);
        }
    }

    // epilogue: BN + ReLU, D layout: row(o) = quad*4+reg, col(n) = lane&15
#pragma unroll
    for (int i = 0; i < 4; i++) {
        int ob = o0 + wo + i * 16 + quad * 4;
        float inv[4], add[4];
#pragma unroll
        for (int r = 0; r < 4; r++) {
            int o = ob + r;
            float iv = gamma[o] * rsqrtf(rvar[o] + 1e-5f);
            inv[r] = iv; add[r] = beta[o] - rmean[o] * iv;
        }
#pragma unroll
        for (int j = 0; j < 2; j++) {
            int n_g = n0 + wn + j * 16 + col;
            int bb = n_g >> 12, hw = n_g & 4095;
            float* op = out + ((long)bb << 20) + hw;
#pragma unroll
            for (int r = 0; r < 4; r++) {
                float v = acc[i][j][r] * inv[r] + add[r];
                v = fmaxf(v, 0.f);
                op[(long)(ob + r) << 12] = v;
            }
        }
    }
}

// ---------------------------------------------------------------------------
extern "C" void kernel_launch(void* const* d_in, const int* in_sizes, int n_in,
                              void* d_out, int out_size, void* d_ws, size_t ws_size,
                              hipStream_t stream) {
    const float* x     = (const float*)d_in[0];
    const float* woff  = (const float*)d_in[1];
    const float* boff  = (const float*)d_in[2];
    const float* wmod  = (const float*)d_in[3];
    const float* bmod  = (const float*)d_in[4];
    const float* wreg  = (const float*)d_in[5];
    const float* gamma = (const float*)d_in[6];
    const float* beta  = (const float*)d_in[7];
    const float* rmean = (const float*)d_in[8];
    const float* rvar  = (const float*)d_in[9];
    float* out = (float*)d_out;

    char* ws = (char*)d_ws;
    // ws map:
    //   [0x000000, 0x024000) wph   bf16  144 KB (A hi, koffg)
    //   [0x040000, 0x064000) wpl   bf16  144 KB (A lo)
    //   [0x080000, 0x23C000) offf  fp32  1.77 MB
    //   [0x240000, 0x360000) wregb bf16  1.18 MB ([o][c*9+t] order)
    //   [0x400000, ...     ) samp  bf16  2304*NL*2 bytes (NL adaptive)
    u16*   wph   = (u16*)(ws);
    u16*   wpl   = (u16*)(ws + 0x40000u);
    float* offf  = (float*)(ws + 0x80000u);
    u16*   wregb = (u16*)(ws + 0x240000u);
    u16*   samp  = (u16*)(ws + 0x400000u);

    int NL = 16384;
    while (NL > 2048 && 0x400000ull + 2304ull * NL * 2ull > (unsigned long long)ws_size)
        NL >>= 1;
    int nchunk = 16384 / NL;

    kprep<<<288,  256, 0, stream>>>(woff, wmod, wph, wpl);
    kwreg<<<2304, 256, 0, stream>>>(wreg, wregb);
    koffg<<<512,  256, 0, stream>>>(x, wph, wpl, boff, bmod, offf);
    for (int c = 0; c < nchunk; c++) {
        ksamp<<<dim3(NL / 64, 8), 256, 0, stream>>>(x, offf, samp, c * NL, NL);
        kgemm<<<dim3(NL / 64, 2), 256, 0, stream>>>(wregb, samp, gamma, beta,
                                                    rmean, rvar, out, c * NL, NL);
    }
}

// Round 10
// 262.183 us; speedup vs baseline: 1.5621x; 1.3422x over previous
//
#include <hip/hip_runtime.h>
#include <hip/hip_bf16.h>

typedef unsigned short u16;
typedef unsigned int   u32;
typedef short   bf16x8 __attribute__((ext_vector_type(8)));  // bf16 carried as i16
typedef float   f32x4  __attribute__((ext_vector_type(4)));

__device__ __forceinline__ float bf2f(u16 u) {
    u32 t = ((u32)u) << 16;
    return __builtin_bit_cast(float, t);
}
__device__ __forceinline__ u32 f2bf(float f) {
    u32 u = __builtin_bit_cast(u32, f);
    return (u + 0x7FFFu + ((u >> 16) & 1u)) >> 16;   // RNE
}
// async global->LDS DMA, 16 B per lane (dst = wave-uniform base + lane*16)
__device__ __forceinline__ void load_lds16(const u16* g, u16* l) {
    __builtin_amdgcn_global_load_lds(
        (const __attribute__((address_space(1))) u32*)(const void*)g,
        (__attribute__((address_space(3))) u32*)(void*)l, 16, 0, 0);
}

// ---------------------------------------------------------------------------
// Kernel 0a: offset/mask conv weights -> hi/lo bf16 A[32][2304], r = t*256+c
// (koffg's K-order). oc 0..17 = w_off, 18..26 = w_mod, 27..31 = 0.
// ---------------------------------------------------------------------------
__global__ void kprep(const float* __restrict__ woff, const float* __restrict__ wmod,
                      u16* __restrict__ ah, u16* __restrict__ al) {
    int i = blockIdx.x * 256 + threadIdx.x;      // 288 blocks -> 73728 exact
    if (i >= 32 * 2304) return;
    int oc = i / 2304, r = i - oc * 2304;
    int t = r >> 8, c = r & 255;
    float v = 0.f;
    if (oc < 18)      v = woff[oc * 2304 + c * 9 + t];
    else if (oc < 27) v = wmod[(oc - 18) * 2304 + c * 9 + t];
    u32 hb = f2bf(v);
    u32 lb = f2bf(v - bf2f((u16)hb));
    ah[i] = (u16)hb;
    al[i] = (u16)lb;
}

// ---------------------------------------------------------------------------
// Kernel 0b: w_reg f32 -> bf16, identity layout [o][c*9+t] (matches samp).
// ---------------------------------------------------------------------------
__global__ void kwreg(const float* __restrict__ wreg, u16* __restrict__ wregb) {
    int i = blockIdx.x * 256 + threadIdx.x;      // 2304 blocks exact
    wregb[i] = (u16)f2bf(wreg[i]);
}

// ---------------------------------------------------------------------------
// Kernel 1: offset/mask conv as MFMA GEMM, M=32 (27 live), N=16384, K=2304.
// hi/lo bf16 split on both operands -> 3 MFMAs, fp32-equivalent precision.
// Fused bias + 2*sigmoid epilogue writes offf directly.
// ---------------------------------------------------------------------------
__global__ __launch_bounds__(256) void koffg(const float* __restrict__ x,
                                             const u16* __restrict__ ah_g,
                                             const u16* __restrict__ al_g,
                                             const float* __restrict__ boff,
                                             const float* __restrict__ bmod,
                                             float* __restrict__ offf) {
    __shared__ u16 Ah[32 * 72], Al[32 * 72];     // 32 oc-rows, 64 k + 8 pad
    __shared__ u16 Bh[32 * 72], Bl[32 * 72];     // 32 n-rows,  64 k + 8 pad
    int tid = threadIdx.x;
    int n0 = blockIdx.x * 32;
    int b = n0 >> 12, h0 = (n0 & 4095) >> 6, w0 = n0 & 63;
    int lane = tid & 63, wv = tid >> 6;
    int mt = wv & 1, nt = wv >> 1;               // 2 m-tiles x 2 n-tiles of 16
    int col = lane & 15, quad = lane >> 4;

    int aoc = tid >> 3, ak0 = (tid & 7) * 8;     // A staging role
    int nl = tid & 31, cl0 = (tid >> 5) * 8;     // B staging role

    f32x4 acc = (f32x4){0.f, 0.f, 0.f, 0.f};

    for (int kt = 0; kt < 36; kt++) {
        int t = kt >> 2, c0 = (kt & 3) << 6;
        int r0 = kt * 64;
        int dy = t / 3 - 1, dx = t % 3 - 1;
        uint4 pah = *(const uint4*)(ah_g + aoc * 2304 + r0 + ak0);
        uint4 pal = *(const uint4*)(al_g + aoc * 2304 + r0 + ak0);
        int hp = h0 + dy, wp = w0 + nl + dx;
        bool vm = ((unsigned)hp < 64u) && ((unsigned)wp < 64u);
        int hc = min(max(hp, 0), 63), wc = min(max(wp, 0), 63);
        const float* xp = x + ((long)(b * 256 + c0 + cl0) << 12) + hc * 64 + wc;
        u32 whi[4], wlo[4];
#pragma unroll
        for (int i = 0; i < 8; i++) {
            float v = vm ? xp[(long)i << 12] : 0.f;
            u32 hb = f2bf(v);
            u32 lb = f2bf(v - bf2f((u16)hb));
            if (i & 1) { whi[i >> 1] |= hb << 16; wlo[i >> 1] |= lb << 16; }
            else       { whi[i >> 1]  = hb;       wlo[i >> 1]  = lb; }
        }
        __syncthreads();
        *(uint4*)&Ah[aoc * 72 + ak0] = pah;
        *(uint4*)&Al[aoc * 72 + ak0] = pal;
        *(uint4*)&Bh[nl * 72 + cl0] = make_uint4(whi[0], whi[1], whi[2], whi[3]);
        *(uint4*)&Bl[nl * 72 + cl0] = make_uint4(wlo[0], wlo[1], wlo[2], wlo[3]);
        __syncthreads();
#pragma unroll
        for (int ks = 0; ks < 2; ks++) {
            int ko = ks * 32 + quad * 8;
            bf16x8 fah = *(const bf16x8*)&Ah[(mt * 16 + col) * 72 + ko];
            bf16x8 fal = *(const bf16x8*)&Al[(mt * 16 + col) * 72 + ko];
            bf16x8 fbh = *(const bf16x8*)&Bh[(nt * 16 + col) * 72 + ko];
            bf16x8 fbl = *(const bf16x8*)&Bl[(nt * 16 + col) * 72 + ko];
            acc = __builtin_amdgcn_mfma_f32_16x16x32_bf16(fah, fbh, acc, 0, 0, 0);
            acc = __builtin_amdgcn_mfma_f32_16x16x32_bf16(fah, fbl, acc, 0, 0, 0);
            acc = __builtin_amdgcn_mfma_f32_16x16x32_bf16(fal, fbh, acc, 0, 0, 0);
        }
    }

    int n = n0 + nt * 16 + col;
#pragma unroll
    for (int r = 0; r < 4; r++) {
        int oc = mt * 16 + quad * 4 + r;
        float s = acc[r];
        if (oc < 18) {
            int ch = 3 * (oc >> 1) + (oc & 1);   // even oc -> dy, odd -> dx
            offf[(ch << 14) + n] = s + boff[oc];
        } else if (oc < 27) {
            float tt = s + bmod[oc - 18];
            int ch = 3 * (oc - 18) + 2;
            offf[(ch << 14) + n] = 2.f / (1.f + __expf(-tt));
        }
    }
}

// ---------------------------------------------------------------------------
// Kernel 2: deformable bilinear sampling -> pre-fragmented samp[rb][nloc][8],
// rb = r>>3, r = c*9+k. Thread = (pixel, one 8-channel group), tap-outer
// loop with scalar tap state (low VGPR -> high occupancy for latency hiding).
// grid = dim3(NL/64, 8), block 256 (64 px x 4 c-groups of 8 ch).
// ---------------------------------------------------------------------------
__global__ __launch_bounds__(256) void ksamp(const float* __restrict__ x,
                                             const float* __restrict__ offf,
                                             u16* __restrict__ samp,
                                             int n0base, int NL) {
    int nl = threadIdx.x & 63, cg = threadIdx.x >> 6;
    int cq = (blockIdx.y << 2) | cg;            // 0..31, 8 channels each
    int nloc = blockIdx.x * 64 + nl;            // 0..NL-1
    int n = n0base + nloc;
    int b = n >> 12, hw = n & 4095, h = hw >> 6, w = hw & 63;

    u32 words[36];
#pragma unroll
    for (int i = 0; i < 36; i++) words[i] = 0u;

    const float* xb = x + ((long)(b * 256 + cq * 8) << 12);
#pragma unroll
    for (int k = 0; k < 9; k++) {
        float dy = offf[((3 * k + 0) << 14) + n];
        float dx = offf[((3 * k + 1) << 14) + n];
        float m  = offf[((3 * k + 2) << 14) + n];
        float py = (float)(h - 1 + (k / 3)) + dy;
        float px = (float)(w - 1 + (k % 3)) + dx;
        float y0f = floorf(py), x0f = floorf(px);
        float wy = py - y0f, wx = px - x0f;
        int iy0 = (int)y0f, ix0 = (int)x0f;
        int iy1 = iy0 + 1, ix1 = ix0 + 1;
        bool vy0 = (unsigned)iy0 < 64u, vy1 = (unsigned)iy1 < 64u;
        bool vx0 = (unsigned)ix0 < 64u, vx1 = (unsigned)ix1 < 64u;
        int cy0 = min(max(iy0, 0), 63), cy1 = min(max(iy1, 0), 63);
        int cx0 = min(max(ix0, 0), 63), cx1 = min(max(ix1, 0), 63);
        int o00 = cy0 * 64 + cx0, o01 = cy0 * 64 + cx1;
        int o10 = cy1 * 64 + cx0, o11 = cy1 * 64 + cx1;
        float a = 1.f - wy, bw = 1.f - wx;
        float s00 = (vy0 && vx0) ? a  * bw * m : 0.f;
        float s01 = (vy0 && vx1) ? a  * wx * m : 0.f;
        float s10 = (vy1 && vx0) ? wy * bw * m : 0.f;
        float s11 = (vy1 && vx1) ? wy * wx * m : 0.f;
#pragma unroll
        for (int cc = 0; cc < 8; cc++) {
            const float* xc = xb + ((long)cc << 12);
            float v = s00 * xc[o00] + s01 * xc[o01] +
                      s10 * xc[o10] + s11 * xc[o11];
            int e = cc * 9 + k;
            words[e >> 1] |= f2bf(v) << ((e & 1) * 16);
        }
    }
    u16* sp = samp + ((long)(cq * 9) * NL + nloc) * 8;
#pragma unroll
    for (int o = 0; o < 9; o++)
        *(uint4*)(sp + (long)o * NL * 8) =
            make_uint4(words[o * 4 + 0], words[o * 4 + 1],
                       words[o * 4 + 2], words[o * 4 + 3]);
}

// ---------------------------------------------------------------------------
// Kernel 3: GEMM for one NL-pixel chunk. Tile 128(o) x 64(n), BK=64.
// m97 recipe: global_load_lds width-16 staging, 2-barrier loop, no padding.
// Al = [o][k] with granule XOR swizzle (phys_g = log_g ^ (o&7)) done on the
// DMA *source* address -> conflict-optimal frag reads, coalescing preserved.
// Bl = [rb][n][8] (k-outer) -> naturally conflict-optimal.
// out[o][n] = relu(BN( sum_r wregb[o][r] * samp[r][nloc] ))
// ---------------------------------------------------------------------------
__global__ __launch_bounds__(256) void kgemm(const u16* __restrict__ wregb,
                                             const u16* __restrict__ samp,
                                             const float* __restrict__ gamma,
                                             const float* __restrict__ beta,
                                             const float* __restrict__ rmean,
                                             const float* __restrict__ rvar,
                                             float* __restrict__ out,
                                             int n0base, int NL) {
    __shared__ u16 Al[128 * 64];   // [o][k] granule-swizzled, 16 KB
    __shared__ u16 Bl[8 * 64 * 8]; // [rb][n][8], 8 KB
    int tid = threadIdx.x;
    int o0 = blockIdx.y * 128;
    int nloc0 = blockIdx.x * 64;
    int n0 = n0base + nloc0;
    int lane = tid & 63, wv = tid >> 6;
    int wo = (wv >> 1) * 64, wn = (wv & 1) * 32;
    int col = lane & 15, quad = lane >> 4;

    f32x4 acc[4][2];
#pragma unroll
    for (int i = 0; i < 4; i++)
#pragma unroll
        for (int j = 0; j < 2; j++) acc[i][j] = (f32x4){0.f, 0.f, 0.f, 0.f};

    for (int kt = 0; kt < 36; kt++) {
        int r0 = kt * 64, rb0 = kt * 8;
        // A: 4 DMA/thread-slot groups (1024 granules of 16 B)
#pragma unroll
        for (int i = 0; i < 4; i++) {
            int cidx = tid + i * 256;
            int o = cidx >> 3, qp = cidx & 7;
            int ql = qp ^ (o & 7);               // source-side XOR swizzle
            load_lds16(wregb + (long)(o0 + o) * 2304 + r0 + ql * 8,
                       &Al[cidx * 8]);
        }
        // B: 2 DMA (512 granules); wave w covers one full rb row -> 1KB/instr
#pragma unroll
        for (int i = 0; i < 2; i++) {
            int cidx = tid + i * 256;
            int rbl = cidx >> 6, nl2 = cidx & 63;
            load_lds16(samp + ((long)(rb0 + rbl) * NL + nloc0 + nl2) * 8,
                       &Bl[cidx * 8]);
        }
        __syncthreads();                         // drains DMA (vmcnt) + prev reads
#pragma unroll
        for (int ks = 0; ks < 2; ks++) {
            bf16x8 af[4], bfr[2];
#pragma unroll
            for (int i = 0; i < 4; i++) {
                int r = wo + i * 16 + col;
                int ph = (ks * 4 + quad) ^ (r & 7);
                af[i] = *(const bf16x8*)&Al[r * 64 + ph * 8];
            }
#pragma unroll
            for (int j = 0; j < 2; j++)
                bfr[j] = *(const bf16x8*)&Bl[((ks * 4 + quad) * 64 +
                                              (wn + j * 16 + col)) * 8];
#pragma unroll
            for (int i = 0; i < 4; i++)
#pragma unroll
                for (int j = 0; j < 2; j++)
                    acc[i][j] = __builtin_amdgcn_mfma_f32_16x16x32_bf16(
                        af[i], bfr[j], acc[i][j], 0, 0, 0);
        }
        __syncthreads();                         // protect LDS from next DMA
    }

    // epilogue: BN + ReLU, D layout: row(o) = quad*4+reg, col(n) = lane&15
#pragma unroll
    for (int i = 0; i < 4; i++) {
        int ob = o0 + wo + i * 16 + quad * 4;
        float inv[4], add[4];
#pragma unroll
        for (int r = 0; r < 4; r++) {
            int o = ob + r;
            float iv = gamma[o] * rsqrtf(rvar[o] + 1e-5f);
            inv[r] = iv; add[r] = beta[o] - rmean[o] * iv;
        }
#pragma unroll
        for (int j = 0; j < 2; j++) {
            int n_g = n0 + wn + j * 16 + col;
            int bb = n_g >> 12, hw = n_g & 4095;
            float* op = out + ((long)bb << 20) + hw;
#pragma unroll
            for (int r = 0; r < 4; r++) {
                float v = acc[i][j][r] * inv[r] + add[r];
                v = fmaxf(v, 0.f);
                op[(long)(ob + r) << 12] = v;
            }
        }
    }
}

// ---------------------------------------------------------------------------
extern "C" void kernel_launch(void* const* d_in, const int* in_sizes, int n_in,
                              void* d_out, int out_size, void* d_ws, size_t ws_size,
                              hipStream_t stream) {
    const float* x     = (const float*)d_in[0];
    const float* woff  = (const float*)d_in[1];
    const float* boff  = (const float*)d_in[2];
    const float* wmod  = (const float*)d_in[3];
    const float* bmod  = (const float*)d_in[4];
    const float* wreg  = (const float*)d_in[5];
    const float* gamma = (const float*)d_in[6];
    const float* beta  = (const float*)d_in[7];
    const float* rmean = (const float*)d_in[8];
    const float* rvar  = (const float*)d_in[9];
    float* out = (float*)d_out;

    char* ws = (char*)d_ws;
    // ws map:
    //   [0x000000, 0x024000) wph   bf16  144 KB (A hi, koffg)
    //   [0x040000, 0x064000) wpl   bf16  144 KB (A lo)
    //   [0x080000, 0x23C000) offf  fp32  1.77 MB
    //   [0x240000, 0x360000) wregb bf16  1.18 MB ([o][c*9+t] order)
    //   [0x400000, ...     ) samp  bf16  2304*NL*2 bytes (NL adaptive)
    u16*   wph   = (u16*)(ws);
    u16*   wpl   = (u16*)(ws + 0x40000u);
    float* offf  = (float*)(ws + 0x80000u);
    u16*   wregb = (u16*)(ws + 0x240000u);
    u16*   samp  = (u16*)(ws + 0x400000u);

    int NL = 16384;
    while (NL > 2048 && 0x400000ull + 2304ull * NL * 2ull > (unsigned long long)ws_size)
        NL >>= 1;
    int nchunk = 16384 / NL;

    kprep<<<288,  256, 0, stream>>>(woff, wmod, wph, wpl);
    kwreg<<<2304, 256, 0, stream>>>(wreg, wregb);
    koffg<<<512,  256, 0, stream>>>(x, wph, wpl, boff, bmod, offf);
    for (int c = 0; c < nchunk; c++) {
        ksamp<<<dim3(NL / 64, 8), 256, 0, stream>>>(x, offf, samp, c * NL, NL);
        kgemm<<<dim3(NL / 64, 2), 256, 0, stream>>>(wregb, samp, gamma, beta,
                                                    rmean, rvar, out, c * NL, NL);
    }
}

// Round 11
// 255.252 us; speedup vs baseline: 1.6046x; 1.0272x over previous
//
#include <hip/hip_runtime.h>
#include <hip/hip_bf16.h>

typedef unsigned short u16;
typedef unsigned int   u32;
typedef short   bf16x8 __attribute__((ext_vector_type(8)));  // bf16 carried as i16
typedef float   f32x4  __attribute__((ext_vector_type(4)));

__device__ __forceinline__ float bf2f(u16 u) {
    u32 t = ((u32)u) << 16;
    return __builtin_bit_cast(float, t);
}
__device__ __forceinline__ u32 f2bf(float f) {
    u32 u = __builtin_bit_cast(u32, f);
    return (u + 0x7FFFu + ((u >> 16) & 1u)) >> 16;   // RNE
}
// async global->LDS DMA, 16 B per lane (dst = wave-uniform base + lane*16)
__device__ __forceinline__ void load_lds16(const u16* g, u16* l) {
    __builtin_amdgcn_global_load_lds(
        (const __attribute__((address_space(1))) u32*)(const void*)g,
        (__attribute__((address_space(3))) u32*)(void*)l, 16, 0, 0);
}

// ---------------------------------------------------------------------------
// GLOBAL K-ORDER (both GEMMs): r = t*256 + c  (tap-major).
// An 8-element K-octet = 8 consecutive channels at ONE tap -> ksamp can
// store each octet as soon as its tap is done (kills the words[36] liveness).
// ---------------------------------------------------------------------------

// Kernel 0a: offset/mask conv weights -> hi/lo bf16 A[32][2304], r = t*256+c
__global__ void kprep(const float* __restrict__ woff, const float* __restrict__ wmod,
                      u16* __restrict__ ah, u16* __restrict__ al) {
    int i = blockIdx.x * 256 + threadIdx.x;      // 288 blocks -> 73728 exact
    if (i >= 32 * 2304) return;
    int oc = i / 2304, r = i - oc * 2304;
    int t = r >> 8, c = r & 255;
    float v = 0.f;
    if (oc < 18)      v = woff[oc * 2304 + c * 9 + t];
    else if (oc < 27) v = wmod[(oc - 18) * 2304 + c * 9 + t];
    u32 hb = f2bf(v);
    u32 lb = f2bf(v - bf2f((u16)hb));
    ah[i] = (u16)hb;
    al[i] = (u16)lb;
}

// Kernel 0b: w_reg f32 -> bf16, layout [o][t*256+c] (matches samp K-order).
__global__ void kwreg(const float* __restrict__ wreg, u16* __restrict__ wregb) {
    int i = blockIdx.x * 256 + threadIdx.x;      // 2304 blocks exact
    int o = i / 2304, r = i - o * 2304;
    int t = r >> 8, c = r & 255;
    wregb[i] = (u16)f2bf(wreg[o * 2304 + c * 9 + t]);
}

// ---------------------------------------------------------------------------
// Kernel 1: offset/mask conv as MFMA GEMM, M=32 (27 live), N=16384, K=2304.
// hi/lo bf16 split on both operands -> 3 MFMAs, fp32-equivalent precision.
// Fused bias + 2*sigmoid epilogue writes offf directly.
// ---------------------------------------------------------------------------
__global__ __launch_bounds__(256) void koffg(const float* __restrict__ x,
                                             const u16* __restrict__ ah_g,
                                             const u16* __restrict__ al_g,
                                             const float* __restrict__ boff,
                                             const float* __restrict__ bmod,
                                             float* __restrict__ offf) {
    __shared__ u16 Ah[32 * 72], Al[32 * 72];     // 32 oc-rows, 64 k + 8 pad
    __shared__ u16 Bh[32 * 72], Bl[32 * 72];     // 32 n-rows,  64 k + 8 pad
    int tid = threadIdx.x;
    int n0 = blockIdx.x * 32;
    int b = n0 >> 12, h0 = (n0 & 4095) >> 6, w0 = n0 & 63;
    int lane = tid & 63, wv = tid >> 6;
    int mt = wv & 1, nt = wv >> 1;               // 2 m-tiles x 2 n-tiles of 16
    int col = lane & 15, quad = lane >> 4;

    int aoc = tid >> 3, ak0 = (tid & 7) * 8;     // A staging role
    int nl = tid & 31, cl0 = (tid >> 5) * 8;     // B staging role

    f32x4 acc = (f32x4){0.f, 0.f, 0.f, 0.f};

    for (int kt = 0; kt < 36; kt++) {
        int t = kt >> 2, c0 = (kt & 3) << 6;
        int r0 = kt * 64;
        int dy = t / 3 - 1, dx = t % 3 - 1;
        uint4 pah = *(const uint4*)(ah_g + aoc * 2304 + r0 + ak0);
        uint4 pal = *(const uint4*)(al_g + aoc * 2304 + r0 + ak0);
        int hp = h0 + dy, wp = w0 + nl + dx;
        bool vm = ((unsigned)hp < 64u) && ((unsigned)wp < 64u);
        int hc = min(max(hp, 0), 63), wc = min(max(wp, 0), 63);
        const float* xp = x + ((long)(b * 256 + c0 + cl0) << 12) + hc * 64 + wc;
        u32 whi[4], wlo[4];
#pragma unroll
        for (int i = 0; i < 8; i++) {
            float v = vm ? xp[(long)i << 12] : 0.f;
            u32 hb = f2bf(v);
            u32 lb = f2bf(v - bf2f((u16)hb));
            if (i & 1) { whi[i >> 1] |= hb << 16; wlo[i >> 1] |= lb << 16; }
            else       { whi[i >> 1]  = hb;       wlo[i >> 1]  = lb; }
        }
        __syncthreads();
        *(uint4*)&Ah[aoc * 72 + ak0] = pah;
        *(uint4*)&Al[aoc * 72 + ak0] = pal;
        *(uint4*)&Bh[nl * 72 + cl0] = make_uint4(whi[0], whi[1], whi[2], whi[3]);
        *(uint4*)&Bl[nl * 72 + cl0] = make_uint4(wlo[0], wlo[1], wlo[2], wlo[3]);
        __syncthreads();
#pragma unroll
        for (int ks = 0; ks < 2; ks++) {
            int ko = ks * 32 + quad * 8;
            bf16x8 fah = *(const bf16x8*)&Ah[(mt * 16 + col) * 72 + ko];
            bf16x8 fal = *(const bf16x8*)&Al[(mt * 16 + col) * 72 + ko];
            bf16x8 fbh = *(const bf16x8*)&Bh[(nt * 16 + col) * 72 + ko];
            bf16x8 fbl = *(const bf16x8*)&Bl[(nt * 16 + col) * 72 + ko];
            acc = __builtin_amdgcn_mfma_f32_16x16x32_bf16(fah, fbh, acc, 0, 0, 0);
            acc = __builtin_amdgcn_mfma_f32_16x16x32_bf16(fah, fbl, acc, 0, 0, 0);
            acc = __builtin_amdgcn_mfma_f32_16x16x32_bf16(fal, fbh, acc, 0, 0, 0);
        }
    }

    int n = n0 + nt * 16 + col;
#pragma unroll
    for (int r = 0; r < 4; r++) {
        int oc = mt * 16 + quad * 4 + r;
        float s = acc[r];
        if (oc < 18) {
            int ch = 3 * (oc >> 1) + (oc & 1);   // even oc -> dy, odd -> dx
            offf[(ch << 14) + n] = s + boff[oc];
        } else if (oc < 27) {
            float tt = s + bmod[oc - 18];
            int ch = 3 * (oc - 18) + 2;
            offf[(ch << 14) + n] = 2.f / (1.f + __expf(-tt));
        }
    }
}

// ---------------------------------------------------------------------------
// Kernel 2: deformable bilinear sampling -> samp[rb][nloc][8] bf16 with
// rb = t*32 + cq (tap-pure octets). Thread = (pixel, 8-channel group cq).
// Tap-outer loop, octet stored per tap -> ~4 live accum regs (low VGPR ->
// high occupancy -> gather latency hidden by TLP).
// grid = dim3(NL/64, 8), block 256 (64 px x 4 c-groups of 8 ch).
// ---------------------------------------------------------------------------
__global__ __launch_bounds__(256) void ksamp(const float* __restrict__ x,
                                             const float* __restrict__ offf,
                                             u16* __restrict__ samp,
                                             int n0base, int NL) {
    int nl = threadIdx.x & 63, cg = threadIdx.x >> 6;
    int cq = (blockIdx.y << 2) | cg;            // 0..31, 8 channels each
    int nloc = blockIdx.x * 64 + nl;            // 0..NL-1
    int n = n0base + nloc;
    int b = n >> 12, hw = n & 4095, h = hw >> 6, w = hw & 63;

    const float* xb = x + ((long)(b * 256 + cq * 8) << 12);
    u16* sp = samp + (long)nloc * 8;

#pragma unroll 1
    for (int k = 0; k < 9; k++) {
        float dy = offf[((3 * k + 0) << 14) + n];
        float dx = offf[((3 * k + 1) << 14) + n];
        float m  = offf[((3 * k + 2) << 14) + n];
        float py = (float)(h - 1 + (k / 3)) + dy;
        float px = (float)(w - 1 + (k % 3)) + dx;
        float y0f = floorf(py), x0f = floorf(px);
        float wy = py - y0f, wx = px - x0f;
        int iy0 = (int)y0f, ix0 = (int)x0f;
        int iy1 = iy0 + 1, ix1 = ix0 + 1;
        bool vy0 = (unsigned)iy0 < 64u, vy1 = (unsigned)iy1 < 64u;
        bool vx0 = (unsigned)ix0 < 64u, vx1 = (unsigned)ix1 < 64u;
        int cy0 = min(max(iy0, 0), 63), cy1 = min(max(iy1, 0), 63);
        int cx0 = min(max(ix0, 0), 63), cx1 = min(max(ix1, 0), 63);
        int o00 = cy0 * 64 + cx0, o01 = cy0 * 64 + cx1;
        int o10 = cy1 * 64 + cx0, o11 = cy1 * 64 + cx1;
        float a = 1.f - wy, bw = 1.f - wx;
        float s00 = (vy0 && vx0) ? a  * bw * m : 0.f;
        float s01 = (vy0 && vx1) ? a  * wx * m : 0.f;
        float s10 = (vy1 && vx0) ? wy * bw * m : 0.f;
        float s11 = (vy1 && vx1) ? wy * wx * m : 0.f;

        u32 wd[4];
#pragma unroll
        for (int cc = 0; cc < 8; cc++) {
            const float* xc = xb + ((long)cc << 12);
            float v = s00 * xc[o00] + s01 * xc[o01] +
                      s10 * xc[o10] + s11 * xc[o11];
            u32 bv = f2bf(v);
            if (cc & 1) wd[cc >> 1] |= bv << 16;
            else        wd[cc >> 1]  = bv;
        }
        int rb = k * 32 + cq;                    // tap-pure octet row
        *(uint4*)(sp + (long)rb * NL * 8) = make_uint4(wd[0], wd[1], wd[2], wd[3]);
    }
}

// ---------------------------------------------------------------------------
// Kernel 3: GEMM for one NL-pixel chunk. Tile 128(o) x 64(n), BK=64.
// m97 recipe: global_load_lds width-16 staging, 2-barrier loop, no padding.
// Al = [o][k] granule-XOR-swizzled on the DMA source; Bl = [rb][n][8].
// K streams linearly in r = t*256+c order (A and B agree).
// out[o][n] = relu(BN( sum_r wregb[o][r] * samp[r][nloc] ))
// ---------------------------------------------------------------------------
__global__ __launch_bounds__(256) void kgemm(const u16* __restrict__ wregb,
                                             const u16* __restrict__ samp,
                                             const float* __restrict__ gamma,
                                             const float* __restrict__ beta,
                                             const float* __restrict__ rmean,
                                             const float* __restrict__ rvar,
                                             float* __restrict__ out,
                                             int n0base, int NL) {
    __shared__ u16 Al[128 * 64];   // [o][k] granule-swizzled, 16 KB
    __shared__ u16 Bl[8 * 64 * 8]; // [rb][n][8], 8 KB
    int tid = threadIdx.x;
    int o0 = blockIdx.y * 128;
    int nloc0 = blockIdx.x * 64;
    int n0 = n0base + nloc0;
    int lane = tid & 63, wv = tid >> 6;
    int wo = (wv >> 1) * 64, wn = (wv & 1) * 32;
    int col = lane & 15, quad = lane >> 4;

    f32x4 acc[4][2];
#pragma unroll
    for (int i = 0; i < 4; i++)
#pragma unroll
        for (int j = 0; j < 2; j++) acc[i][j] = (f32x4){0.f, 0.f, 0.f, 0.f};

    for (int kt = 0; kt < 36; kt++) {
        int r0 = kt * 64, rb0 = kt * 8;
#pragma unroll
        for (int i = 0; i < 4; i++) {
            int cidx = tid + i * 256;
            int o = cidx >> 3, qp = cidx & 7;
            int ql = qp ^ (o & 7);               // source-side XOR swizzle
            load_lds16(wregb + (long)(o0 + o) * 2304 + r0 + ql * 8,
                       &Al[cidx * 8]);
        }
#pragma unroll
        for (int i = 0; i < 2; i++) {
            int cidx = tid + i * 256;
            int rbl = cidx >> 6, nl2 = cidx & 63;
            load_lds16(samp + ((long)(rb0 + rbl) * NL + nloc0 + nl2) * 8,
                       &Bl[cidx * 8]);
        }
        __syncthreads();                         // drains DMA + prev frag reads
#pragma unroll
        for (int ks = 0; ks < 2; ks++) {
            bf16x8 af[4], bfr[2];
#pragma unroll
            for (int i = 0; i < 4; i++) {
                int r = wo + i * 16 + col;
                int ph = (ks * 4 + quad) ^ (r & 7);
                af[i] = *(const bf16x8*)&Al[r * 64 + ph * 8];
            }
#pragma unroll
            for (int j = 0; j < 2; j++)
                bfr[j] = *(const bf16x8*)&Bl[((ks * 4 + quad) * 64 +
                                              (wn + j * 16 + col)) * 8];
#pragma unroll
            for (int i = 0; i < 4; i++)
#pragma unroll
                for (int j = 0; j < 2; j++)
                    acc[i][j] = __builtin_amdgcn_mfma_f32_16x16x32_bf16(
                        af[i], bfr[j], acc[i][j], 0, 0, 0);
        }
        __syncthreads();                         // protect LDS from next DMA
    }

    // epilogue: BN + ReLU, D layout: row(o) = quad*4+reg, col(n) = lane&15
#pragma unroll
    for (int i = 0; i < 4; i++) {
        int ob = o0 + wo + i * 16 + quad * 4;
        float inv[4], add[4];
#pragma unroll
        for (int r = 0; r < 4; r++) {
            int o = ob + r;
            float iv = gamma[o] * rsqrtf(rvar[o] + 1e-5f);
            inv[r] = iv; add[r] = beta[o] - rmean[o] * iv;
        }
#pragma unroll
        for (int j = 0; j < 2; j++) {
            int n_g = n0 + wn + j * 16 + col;
            int bb = n_g >> 12, hw = n_g & 4095;
            float* op = out + ((long)bb << 20) + hw;
#pragma unroll
            for (int r = 0; r < 4; r++) {
                float v = acc[i][j][r] * inv[r] + add[r];
                v = fmaxf(v, 0.f);
                op[(long)(ob + r) << 12] = v;
            }
        }
    }
}

// ---------------------------------------------------------------------------
extern "C" void kernel_launch(void* const* d_in, const int* in_sizes, int n_in,
                              void* d_out, int out_size, void* d_ws, size_t ws_size,
                              hipStream_t stream) {
    const float* x     = (const float*)d_in[0];
    const float* woff  = (const float*)d_in[1];
    const float* boff  = (const float*)d_in[2];
    const float* wmod  = (const float*)d_in[3];
    const float* bmod  = (const float*)d_in[4];
    const float* wreg  = (const float*)d_in[5];
    const float* gamma = (const float*)d_in[6];
    const float* beta  = (const float*)d_in[7];
    const float* rmean = (const float*)d_in[8];
    const float* rvar  = (const float*)d_in[9];
    float* out = (float*)d_out;

    char* ws = (char*)d_ws;
    // ws map:
    //   [0x000000, 0x024000) wph   bf16  144 KB (A hi, koffg)
    //   [0x040000, 0x064000) wpl   bf16  144 KB (A lo)
    //   [0x080000, 0x23C000) offf  fp32  1.77 MB
    //   [0x240000, 0x360000) wregb bf16  1.18 MB ([o][t*256+c] order)
    //   [0x400000, ...     ) samp  bf16  2304*NL*2 bytes (NL adaptive)
    u16*   wph   = (u16*)(ws);
    u16*   wpl   = (u16*)(ws + 0x40000u);
    float* offf  = (float*)(ws + 0x80000u);
    u16*   wregb = (u16*)(ws + 0x240000u);
    u16*   samp  = (u16*)(ws + 0x400000u);

    int NL = 16384;
    while (NL > 2048 && 0x400000ull + 2304ull * NL * 2ull > (unsigned long long)ws_size)
        NL >>= 1;
    int nchunk = 16384 / NL;

    kprep<<<288,  256, 0, stream>>>(woff, wmod, wph, wpl);
    kwreg<<<2304, 256, 0, stream>>>(wreg, wregb);
    koffg<<<512,  256, 0, stream>>>(x, wph, wpl, boff, bmod, offf);
    for (int c = 0; c < nchunk; c++) {
        ksamp<<<dim3(NL / 64, 8), 256, 0, stream>>>(x, offf, samp, c * NL, NL);
        kgemm<<<dim3(NL / 64, 2), 256, 0, stream>>>(wregb, samp, gamma, beta,
                                                    rmean, rvar, out, c * NL, NL);
    }
}

// Round 12
// 253.127 us; speedup vs baseline: 1.6180x; 1.0084x over previous
//
#include <hip/hip_runtime.h>
#include <hip/hip_bf16.h>

typedef unsigned short u16;
typedef unsigned int   u32;
typedef short   bf16x8 __attribute__((ext_vector_type(8)));  // bf16 carried as i16
typedef float   f32x4  __attribute__((ext_vector_type(4)));

__device__ __forceinline__ float bf2f(u16 u) {
    u32 t = ((u32)u) << 16;
    return __builtin_bit_cast(float, t);
}
__device__ __forceinline__ u32 f2bf(float f) {
    u32 u = __builtin_bit_cast(u32, f);
    return (u + 0x7FFFu + ((u >> 16) & 1u)) >> 16;   // RNE
}
// async global->LDS DMA, 16 B per lane (dst = wave-uniform base + lane*16)
__device__ __forceinline__ void load_lds16(const u16* g, u16* l) {
    __builtin_amdgcn_global_load_lds(
        (const __attribute__((address_space(1))) u32*)(const void*)g,
        (__attribute__((address_space(3))) u32*)(void*)l, 16, 0, 0);
}

// ---------------------------------------------------------------------------
// GLOBAL K-ORDER (both GEMMs): r = t*256 + c  (tap-major).
// ---------------------------------------------------------------------------

// Kernel 0a: offset/mask conv weights -> hi/lo bf16 A[32][2304], r = t*256+c
__global__ void kprep(const float* __restrict__ woff, const float* __restrict__ wmod,
                      u16* __restrict__ ah, u16* __restrict__ al) {
    int i = blockIdx.x * 256 + threadIdx.x;      // 288 blocks -> 73728 exact
    if (i >= 32 * 2304) return;
    int oc = i / 2304, r = i - oc * 2304;
    int t = r >> 8, c = r & 255;
    float v = 0.f;
    if (oc < 18)      v = woff[oc * 2304 + c * 9 + t];
    else if (oc < 27) v = wmod[(oc - 18) * 2304 + c * 9 + t];
    u32 hb = f2bf(v);
    u32 lb = f2bf(v - bf2f((u16)hb));
    ah[i] = (u16)hb;
    al[i] = (u16)lb;
}

// Kernel 0b: w_reg f32 -> bf16, layout [o][t*256+c] (matches samp K-order).
__global__ void kwreg(const float* __restrict__ wreg, u16* __restrict__ wregb) {
    int i = blockIdx.x * 256 + threadIdx.x;      // 2304 blocks exact
    int o = i / 2304, r = i - o * 2304;
    int t = r >> 8, c = r & 255;
    wregb[i] = (u16)f2bf(wreg[o * 2304 + c * 9 + t]);
}

// ---------------------------------------------------------------------------
// Kernel 1: offset/mask conv as MFMA GEMM, M=32 (27 live), N=16384, K=2304.
// hi/lo bf16 split on both operands -> 3 MFMAs, fp32-equivalent precision.
// Fused bias + 2*sigmoid epilogue writes offf directly.
// ---------------------------------------------------------------------------
__global__ __launch_bounds__(256) void koffg(const float* __restrict__ x,
                                             const u16* __restrict__ ah_g,
                                             const u16* __restrict__ al_g,
                                             const float* __restrict__ boff,
                                             const float* __restrict__ bmod,
                                             float* __restrict__ offf) {
    __shared__ u16 Ah[32 * 72], Al[32 * 72];     // 32 oc-rows, 64 k + 8 pad
    __shared__ u16 Bh[32 * 72], Bl[32 * 72];     // 32 n-rows,  64 k + 8 pad
    int tid = threadIdx.x;
    int n0 = blockIdx.x * 32;
    int b = n0 >> 12, h0 = (n0 & 4095) >> 6, w0 = n0 & 63;
    int lane = tid & 63, wv = tid >> 6;
    int mt = wv & 1, nt = wv >> 1;               // 2 m-tiles x 2 n-tiles of 16
    int col = lane & 15, quad = lane >> 4;

    int aoc = tid >> 3, ak0 = (tid & 7) * 8;     // A staging role
    int nl = tid & 31, cl0 = (tid >> 5) * 8;     // B staging role

    f32x4 acc = (f32x4){0.f, 0.f, 0.f, 0.f};

    for (int kt = 0; kt < 36; kt++) {
        int t = kt >> 2, c0 = (kt & 3) << 6;
        int r0 = kt * 64;
        int dy = t / 3 - 1, dx = t % 3 - 1;
        uint4 pah = *(const uint4*)(ah_g + aoc * 2304 + r0 + ak0);
        uint4 pal = *(const uint4*)(al_g + aoc * 2304 + r0 + ak0);
        int hp = h0 + dy, wp = w0 + nl + dx;
        bool vm = ((unsigned)hp < 64u) && ((unsigned)wp < 64u);
        int hc = min(max(hp, 0), 63), wc = min(max(wp, 0), 63);
        const float* xp = x + ((long)(b * 256 + c0 + cl0) << 12) + hc * 64 + wc;
        u32 whi[4], wlo[4];
#pragma unroll
        for (int i = 0; i < 8; i++) {
            float v = vm ? xp[(long)i << 12] : 0.f;
            u32 hb = f2bf(v);
            u32 lb = f2bf(v - bf2f((u16)hb));
            if (i & 1) { whi[i >> 1] |= hb << 16; wlo[i >> 1] |= lb << 16; }
            else       { whi[i >> 1]  = hb;       wlo[i >> 1]  = lb; }
        }
        __syncthreads();
        *(uint4*)&Ah[aoc * 72 + ak0] = pah;
        *(uint4*)&Al[aoc * 72 + ak0] = pal;
        *(uint4*)&Bh[nl * 72 + cl0] = make_uint4(whi[0], whi[1], whi[2], whi[3]);
        *(uint4*)&Bl[nl * 72 + cl0] = make_uint4(wlo[0], wlo[1], wlo[2], wlo[3]);
        __syncthreads();
#pragma unroll
        for (int ks = 0; ks < 2; ks++) {
            int ko = ks * 32 + quad * 8;
            bf16x8 fah = *(const bf16x8*)&Ah[(mt * 16 + col) * 72 + ko];
            bf16x8 fal = *(const bf16x8*)&Al[(mt * 16 + col) * 72 + ko];
            bf16x8 fbh = *(const bf16x8*)&Bh[(nt * 16 + col) * 72 + ko];
            bf16x8 fbl = *(const bf16x8*)&Bl[(nt * 16 + col) * 72 + ko];
            acc = __builtin_amdgcn_mfma_f32_16x16x32_bf16(fah, fbh, acc, 0, 0, 0);
            acc = __builtin_amdgcn_mfma_f32_16x16x32_bf16(fah, fbl, acc, 0, 0, 0);
            acc = __builtin_amdgcn_mfma_f32_16x16x32_bf16(fal, fbh, acc, 0, 0, 0);
        }
    }

    int n = n0 + nt * 16 + col;
#pragma unroll
    for (int r = 0; r < 4; r++) {
        int oc = mt * 16 + quad * 4 + r;
        float s = acc[r];
        if (oc < 18) {
            int ch = 3 * (oc >> 1) + (oc & 1);   // even oc -> dy, odd -> dx
            offf[(ch << 14) + n] = s + boff[oc];
        } else if (oc < 27) {
            float tt = s + bmod[oc - 18];
            int ch = 3 * (oc - 18) + 2;
            offf[(ch << 14) + n] = 2.f / (1.f + __expf(-tt));
        }
    }
}

// ---------------------------------------------------------------------------
// Kernel 2: deformable bilinear sampling -> samp[rb][nloc][8] bf16 with
// rb = t*32 + cq (tap-pure octets). Thread = (pixel, 8-channel group cq).
// Outer loop over 3 TAP-ROWS (taps {0,1,2},{3,4,5},{6,7,8}): row-bands are
// nearly disjoint across groups (offsets are small) -> each x row read ~once,
// while live state stays at 3 octets + 3 tap states (~60 VGPR, ~8 waves/SIMD).
// grid = dim3(NL/64, 8), block 256 (64 px x 4 c-groups of 8 ch).
// ---------------------------------------------------------------------------
__global__ __launch_bounds__(256) void ksamp(const float* __restrict__ x,
                                             const float* __restrict__ offf,
                                             u16* __restrict__ samp,
                                             int n0base, int NL) {
    int nl = threadIdx.x & 63, cg = threadIdx.x >> 6;
    int cq = (blockIdx.y << 2) | cg;            // 0..31, 8 channels each
    int nloc = blockIdx.x * 64 + nl;            // 0..NL-1
    int n = n0base + nloc;
    int b = n >> 12, hw = n & 4095, h = hw >> 6, w = hw & 63;

    const float* xb = x + ((long)(b * 256 + cq * 8) << 12);
    u16* sp = samp + (long)nloc * 8;

#pragma unroll 1
    for (int g = 0; g < 3; g++) {               // tap row ky = g
        int   o00[3], o01[3], o10[3], o11[3];
        float s00[3], s01[3], s10[3], s11[3];
#pragma unroll
        for (int t = 0; t < 3; t++) {
            int k = g * 3 + t;
            float dy = offf[((3 * k + 0) << 14) + n];
            float dx = offf[((3 * k + 1) << 14) + n];
            float m  = offf[((3 * k + 2) << 14) + n];
            float py = (float)(h - 1 + g) + dy;
            float px = (float)(w - 1 + t) + dx;
            float y0f = floorf(py), x0f = floorf(px);
            float wy = py - y0f, wx = px - x0f;
            int iy0 = (int)y0f, ix0 = (int)x0f;
            int iy1 = iy0 + 1, ix1 = ix0 + 1;
            bool vy0 = (unsigned)iy0 < 64u, vy1 = (unsigned)iy1 < 64u;
            bool vx0 = (unsigned)ix0 < 64u, vx1 = (unsigned)ix1 < 64u;
            int cy0 = min(max(iy0, 0), 63), cy1 = min(max(iy1, 0), 63);
            int cx0 = min(max(ix0, 0), 63), cx1 = min(max(ix1, 0), 63);
            o00[t] = cy0 * 64 + cx0; o01[t] = cy0 * 64 + cx1;
            o10[t] = cy1 * 64 + cx0; o11[t] = cy1 * 64 + cx1;
            float a = 1.f - wy, bw = 1.f - wx;
            s00[t] = (vy0 && vx0) ? a  * bw * m : 0.f;
            s01[t] = (vy0 && vx1) ? a  * wx * m : 0.f;
            s10[t] = (vy1 && vx0) ? wy * bw * m : 0.f;
            s11[t] = (vy1 && vx1) ? wy * wx * m : 0.f;
        }

        u32 wd[3][4];
#pragma unroll
        for (int cc = 0; cc < 8; cc++) {        // channel-inner: 12 gathers
            const float* xc = xb + ((long)cc << 12);   // in a 3-row window
#pragma unroll
            for (int t = 0; t < 3; t++) {
                float v = s00[t] * xc[o00[t]] + s01[t] * xc[o01[t]] +
                          s10[t] * xc[o10[t]] + s11[t] * xc[o11[t]];
                u32 bv = f2bf(v);
                if (cc & 1) wd[t][cc >> 1] |= bv << 16;
                else        wd[t][cc >> 1]  = bv;
            }
        }
#pragma unroll
        for (int t = 0; t < 3; t++) {
            int rb = (g * 3 + t) * 32 + cq;     // tap-pure octet row
            *(uint4*)(sp + (long)rb * NL * 8) =
                make_uint4(wd[t][0], wd[t][1], wd[t][2], wd[t][3]);
        }
    }
}

// ---------------------------------------------------------------------------
// Kernel 3: GEMM for one NL-pixel chunk. Tile 128(o) x 64(n), BK=64.
// m97 recipe: global_load_lds width-16 staging, 2-barrier loop, no padding.
// Al = [o][k] granule-XOR-swizzled on the DMA source; Bl = [rb][n][8].
// K streams linearly in r = t*256+c order (A and B agree).
// out[o][n] = relu(BN( sum_r wregb[o][r] * samp[r][nloc] ))
// ---------------------------------------------------------------------------
__global__ __launch_bounds__(256) void kgemm(const u16* __restrict__ wregb,
                                             const u16* __restrict__ samp,
                                             const float* __restrict__ gamma,
                                             const float* __restrict__ beta,
                                             const float* __restrict__ rmean,
                                             const float* __restrict__ rvar,
                                             float* __restrict__ out,
                                             int n0base, int NL) {
    __shared__ u16 Al[128 * 64];   // [o][k] granule-swizzled, 16 KB
    __shared__ u16 Bl[8 * 64 * 8]; // [rb][n][8], 8 KB
    int tid = threadIdx.x;
    int o0 = blockIdx.y * 128;
    int nloc0 = blockIdx.x * 64;
    int n0 = n0base + nloc0;
    int lane = tid & 63, wv = tid >> 6;
    int wo = (wv >> 1) * 64, wn = (wv & 1) * 32;
    int col = lane & 15, quad = lane >> 4;

    f32x4 acc[4][2];
#pragma unroll
    for (int i = 0; i < 4; i++)
#pragma unroll
        for (int j = 0; j < 2; j++) acc[i][j] = (f32x4){0.f, 0.f, 0.f, 0.f};

    for (int kt = 0; kt < 36; kt++) {
        int r0 = kt * 64, rb0 = kt * 8;
#pragma unroll
        for (int i = 0; i < 4; i++) {
            int cidx = tid + i * 256;
            int o = cidx >> 3, qp = cidx & 7;
            int ql = qp ^ (o & 7);               // source-side XOR swizzle
            load_lds16(wregb + (long)(o0 + o) * 2304 + r0 + ql * 8,
                       &Al[cidx * 8]);
        }
#pragma unroll
        for (int i = 0; i < 2; i++) {
            int cidx = tid + i * 256;
            int rbl = cidx >> 6, nl2 = cidx & 63;
            load_lds16(samp + ((long)(rb0 + rbl) * NL + nloc0 + nl2) * 8,
                       &Bl[cidx * 8]);
        }
        __syncthreads();                         // drains DMA + prev frag reads
#pragma unroll
        for (int ks = 0; ks < 2; ks++) {
            bf16x8 af[4], bfr[2];
#pragma unroll
            for (int i = 0; i < 4; i++) {
                int r = wo + i * 16 + col;
                int ph = (ks * 4 + quad) ^ (r & 7);
                af[i] = *(const bf16x8*)&Al[r * 64 + ph * 8];
            }
#pragma unroll
            for (int j = 0; j < 2; j++)
                bfr[j] = *(const bf16x8*)&Bl[((ks * 4 + quad) * 64 +
                                              (wn + j * 16 + col)) * 8];
#pragma unroll
            for (int i = 0; i < 4; i++)
#pragma unroll
                for (int j = 0; j < 2; j++)
                    acc[i][j] = __builtin_amdgcn_mfma_f32_16x16x32_bf16(
                        af[i], bfr[j], acc[i][j], 0, 0, 0);
        }
        __syncthreads();                         // protect LDS from next DMA
    }

    // epilogue: BN + ReLU, D layout: row(o) = quad*4+reg, col(n) = lane&15
#pragma unroll
    for (int i = 0; i < 4; i++) {
        int ob = o0 + wo + i * 16 + quad * 4;
        float inv[4], add[4];
#pragma unroll
        for (int r = 0; r < 4; r++) {
            int o = ob + r;
            float iv = gamma[o] * rsqrtf(rvar[o] + 1e-5f);
            inv[r] = iv; add[r] = beta[o] - rmean[o] * iv;
        }
#pragma unroll
        for (int j = 0; j < 2; j++) {
            int n_g = n0 + wn + j * 16 + col;
            int bb = n_g >> 12, hw = n_g & 4095;
            float* op = out + ((long)bb << 20) + hw;
#pragma unroll
            for (int r = 0; r < 4; r++) {
                float v = acc[i][j][r] * inv[r] + add[r];
                v = fmaxf(v, 0.f);
                op[(long)(ob + r) << 12] = v;
            }
        }
    }
}

// ---------------------------------------------------------------------------
extern "C" void kernel_launch(void* const* d_in, const int* in_sizes, int n_in,
                              void* d_out, int out_size, void* d_ws, size_t ws_size,
                              hipStream_t stream) {
    const float* x     = (const float*)d_in[0];
    const float* woff  = (const float*)d_in[1];
    const float* boff  = (const float*)d_in[2];
    const float* wmod  = (const float*)d_in[3];
    const float* bmod  = (const float*)d_in[4];
    const float* wreg  = (const float*)d_in[5];
    const float* gamma = (const float*)d_in[6];
    const float* beta  = (const float*)d_in[7];
    const float* rmean = (const float*)d_in[8];
    const float* rvar  = (const float*)d_in[9];
    float* out = (float*)d_out;

    char* ws = (char*)d_ws;
    // ws map:
    //   [0x000000, 0x024000) wph   bf16  144 KB (A hi, koffg)
    //   [0x040000, 0x064000) wpl   bf16  144 KB (A lo)
    //   [0x080000, 0x23C000) offf  fp32  1.77 MB
    //   [0x240000, 0x360000) wregb bf16  1.18 MB ([o][t*256+c] order)
    //   [0x400000, ...     ) samp  bf16  2304*NL*2 bytes (NL adaptive)
    u16*   wph   = (u16*)(ws);
    u16*   wpl   = (u16*)(ws + 0x40000u);
    float* offf  = (float*)(ws + 0x80000u);
    u16*   wregb = (u16*)(ws + 0x240000u);
    u16*   samp  = (u16*)(ws + 0x400000u);

    int NL = 16384;
    while (NL > 2048 && 0x400000ull + 2304ull * NL * 2ull > (unsigned long long)ws_size)
        NL >>= 1;
    int nchunk = 16384 / NL;

    kprep<<<288,  256, 0, stream>>>(woff, wmod, wph, wpl);
    kwreg<<<2304, 256, 0, stream>>>(wreg, wregb);
    koffg<<<512,  256, 0, stream>>>(x, wph, wpl, boff, bmod, offf);
    for (int c = 0; c < nchunk; c++) {
        ksamp<<<dim3(NL / 64, 8), 256, 0, stream>>>(x, offf, samp, c * NL, NL);
        kgemm<<<dim3(NL / 64, 2), 256, 0, stream>>>(wregb, samp, gamma, beta,
                                                    rmean, rvar, out, c * NL, NL);
    }
}